// Round 10
// baseline (410.896 us; speedup 1.0000x reference)
//
#include <hip/hip_runtime.h>

// B=32, LV=196, LT=40, D=512, H=8, DH=64

typedef unsigned int u32;
typedef unsigned short u16;
typedef __attribute__((ext_vector_type(8))) short bf16x8;
typedef __attribute__((ext_vector_type(4))) float f32x4;

#define DEV __device__ __forceinline__

DEV u16 f2bf(float f) {
  u32 u = __builtin_bit_cast(u32, f);
  u = (u + 0x7FFFu + ((u >> 16) & 1u)) >> 16;
  return (u16)u;
}
DEV float bf2f(u16 h) { u32 u = ((u32)h) << 16; return __builtin_bit_cast(float, u); }
// monotonic float<->u32 encoding for atomicMax on floats (enc(x)>enc(y) iff x>y)
DEV u32 encf(float f) { u32 u = __builtin_bit_cast(u32, f); return (u & 0x80000000u) ? ~u : (u | 0x80000000u); }
DEV float decf(u32 e) { u32 u = (e & 0x80000000u) ? (e & 0x7FFFFFFFu) : ~e; return __builtin_bit_cast(float, u); }

// async global->LDS, 16B per lane. LDS dest = wave-uniform base + lane*16 (HW).
// Global src is PER-LANE: pre-swizzled so the swizzled ds_read is conflict-free.
DEV void gll16(const u16* g, u16* l) {
  __builtin_amdgcn_global_load_lds(
      (const __attribute__((address_space(1))) void*)g,
      (__attribute__((address_space(3))) void*)l, 16, 0, 0);
}

#define VMCNT0 asm volatile("s_waitcnt vmcnt(0)" ::: "memory")
#define SBAR __builtin_amdgcn_s_barrier()

// ---------------- fused prep: all casts + transposes + sentbias + biasq + init ----------------
DEV void cast8(const float* __restrict__ in, u16* __restrict__ out, int i) {
  const float4* p = (const float4*)in + (size_t)i * 2;
  float4 a = p[0], b = p[1];
  u16 t[8] = {f2bf(a.x), f2bf(a.y), f2bf(a.z), f2bf(a.w),
              f2bf(b.x), f2bf(b.y), f2bf(b.z), f2bf(b.w)};
  *(uint4*)(out + (size_t)i * 8) = *(uint4*)t;
}

DEV void tcast(const float* __restrict__ in, u16* __restrict__ out, int t, int tid, float* sm) {
  int bx = t & 15, by = t >> 4;
  int tx = tid & 31, ty = tid >> 5;
  float (*tt)[33] = (float(*)[33])sm;
  for (int i = ty; i < 32; i += 8) tt[i][tx] = in[(size_t)(by * 32 + i) * 512 + bx * 32 + tx];
  __syncthreads();
  for (int i = ty; i < 32; i += 8) out[(size_t)(bx * 32 + i) * 512 + by * 32 + tx] = f2bf(tt[tx][i]);
}

__global__ __launch_bounds__(256) void k_prep(
    const float* __restrict__ bef, const float* __restrict__ aft,
    const float* __restrict__ sent, const float* __restrict__ masks,
    const float* __restrict__ conv1_w, const float* __restrict__ conv1_b,
    const float* __restrict__ in_proj_w, const float* __restrict__ out_proj_w,
    const float* __restrict__ conv2_w, const float* __restrict__ conv2_b,
    const float* __restrict__ q_w, const float* __restrict__ q_b,
    const float* __restrict__ k_w,
    u16* __restrict__ bef16, u16* __restrict__ aft16,
    u16* __restrict__ inproj16, u16* __restrict__ kw16, u16* __restrict__ qw16,
    u16* __restrict__ w1a16, u16* __restrict__ wcT16, u16* __restrict__ woT16,
    float* __restrict__ biasb, float* __restrict__ biasq,
    uint4* __restrict__ maxbuf) {
  __shared__ float smemf[1056];
  const int blk = blockIdx.x, tid = threadIdx.x;
  if (blk < 32) {
    // sentbias: masked text mean -> conv1 text-half bias, b = blk
    int b = blk;
    float* sm = smemf;
    for (int d = tid; d < 512; d += 256) {
      float s = 0.f;
#pragma unroll 8
      for (int t = 0; t < 40; ++t) s += sent[(size_t)b * 40 * 512 + (size_t)t * 512 + d] * masks[b * 40 + t];
      sm[d] = s * (1.0f / 40.0f);
    }
    __syncthreads();
    for (int o = tid; o < 512; o += 256) {
      const float* wr = conv1_w + (size_t)o * 1024 + 512;
      float acc = conv1_b[o];
#pragma unroll 8
      for (int c = 0; c < 512; ++c) acc += sm[c] * wr[c];
      biasb[b * 512 + o] = acc;
    }
  } else if (blk < 424) {
    // init maxbuf: 392 blocks * 256 = 100352 uint4
    maxbuf[(size_t)(blk - 32) * 256 + tid] = (uint4){0u, 0u, 0u, 0u};
  } else if (blk < 426) {
    // biasq
    int j = (blk - 424) * 256 + tid;
    if (j < 512) {
      const float* wr = q_w + (size_t)j * 512;
      float acc = q_b[j];
#pragma unroll 8
      for (int d = 0; d < 512; ++d) acc += wr[d] * conv2_b[d];
      biasq[j] = acc;
    }
  } else if (blk < 1994) {
    cast8(bef, bef16, (blk - 426) * 256 + tid);       // 401408 groups
  } else if (blk < 3562) {
    cast8(aft, aft16, (blk - 1994) * 256 + tid);
  } else if (blk < 3946) {
    cast8(in_proj_w, inproj16, (blk - 3562) * 256 + tid);
  } else if (blk < 4074) {
    cast8(k_w, kw16, (blk - 3946) * 256 + tid);
  } else if (blk < 4202) {
    cast8(q_w, qw16, (blk - 4074) * 256 + tid);
  } else if (blk < 4330) {
    // conv1a: image half of conv1_w
    int i = (blk - 4202) * 256 + tid;
    int o = i >> 6, c0 = (i & 63) * 8;
    const float* p = conv1_w + (size_t)o * 1024 + c0;
    u16 t[8];
#pragma unroll
    for (int j = 0; j < 8; ++j) t[j] = f2bf(p[j]);
    *(uint4*)(w1a16 + (size_t)o * 512 + c0) = *(uint4*)t;
  } else if (blk < 4586) {
    tcast(conv2_w, wcT16, blk - 4330, tid, smemf);
  } else {
    tcast(out_proj_w, woT16, blk - 4586, tid, smemf);
  }
}

// ---------------- bf16 MFMA GEMM, m97-style 128x128 tile: C = X(MxK) @ W(NxK)^T, K=512 ----------------
// (R6 structure, proven, unchanged.)
DEV void stage_g3(const u16* __restrict__ xb, const u16* __restrict__ wb,
                  u16* Xb, u16* Wb, int wave, int lane, int koff, int scol) {
  int r8 = lane >> 3;
#pragma unroll
  for (int i = 0; i < 8; ++i) {
    int s = wave + i * 4;
    if (s < 16) gll16(xb + (size_t)(s * 8 + r8) * 512 + koff + scol, Xb + s * 512);
    else        gll16(wb + (size_t)((s - 16) * 8 + r8) * 512 + koff + scol, Wb + (s - 16) * 512);
  }
}

DEV void comp_g3(const u16* Xb, const u16* Wb, int wr, int wc, int quad, int l15, int rsw,
                 f32x4 (&acc)[4][4]) {
#pragma unroll
  for (int kk = 0; kk < 64; kk += 32) {
    int co = (kk | (quad << 3)) ^ rsw;
    bf16x8 af[4];
#pragma unroll
    for (int s = 0; s < 4; ++s)
      af[s] = *(const bf16x8*)&Xb[(wr * 64 + s * 16 + l15) * 64 + co];
#pragma unroll
    for (int nt = 0; nt < 4; ++nt) {
      bf16x8 b = *(const bf16x8*)&Wb[(wc * 64 + nt * 16 + l15) * 64 + co];
#pragma unroll
      for (int s = 0; s < 4; ++s)
        acc[s][nt] = __builtin_amdgcn_mfma_f32_16x16x32_bf16(af[s], b, acc[s][nt], 0, 0, 0);
    }
  }
}

// biasMode: 0 none, 1 per-col bias[col], 2 per-batch-row bias[(row/196)*512+col]
__global__ __launch_bounds__(256) void k_gemm3d(
    const u16* __restrict__ X1, const u16* __restrict__ W1, u16* __restrict__ o1,
    const float* __restrict__ b1, int nbx1, int N1, int m1, int nblk1,
    const u16* __restrict__ X2, const u16* __restrict__ W2, u16* __restrict__ o2,
    const float* __restrict__ b2, int nbx2, int N2, int m2) {
  __shared__ u16 Xl0[128 * 64], Xl1[128 * 64];
  __shared__ u16 Wl0[128 * 64], Wl1[128 * 64];
  int g = blockIdx.x;
  const u16 *X, *W; u16* out; const float* bias; int N, biasMode, bx, by;
  if (g < nblk1) {
    X = X1; W = W1; out = o1; bias = b1; N = N1; biasMode = m1;
    bx = g % nbx1; by = g / nbx1;
  } else {
    g -= nblk1;
    X = X2; W = W2; out = o2; bias = b2; N = N2; biasMode = m2;
    bx = g % nbx2; by = g / nbx2;
  }
  int tid = threadIdx.x;
  int tileM = bx * 128, tileN = by * 128;
  int wave = tid >> 6, lane = tid & 63, quad = lane >> 4, l15 = lane & 15;
  int wr = wave >> 1, wc = wave & 1;
  const int rsw = (l15 & 7) << 3;                              // read-side swizzle (u16 units)
  const int scol = (((lane & 7) ^ ((lane >> 3) & 7)) << 3);    // source-side swizzle (u16 units)
  f32x4 z = {0.f, 0.f, 0.f, 0.f};
  f32x4 acc[4][4];
#pragma unroll
  for (int s = 0; s < 4; ++s)
#pragma unroll
    for (int nt = 0; nt < 4; ++nt) acc[s][nt] = z;
  const u16* xb = X + (size_t)tileM * 512;
  const u16* wb = W + (size_t)tileN * 512;

  stage_g3(xb, wb, Xl0, Wl0, wave, lane, 0, scol);
  VMCNT0; SBAR;
#pragma unroll
  for (int kc = 0; kc < 8; kc += 2) {
    stage_g3(xb, wb, Xl1, Wl1, wave, lane, (kc + 1) * 64, scol);
    comp_g3(Xl0, Wl0, wr, wc, quad, l15, rsw, acc);
    VMCNT0; SBAR;
    if (kc + 2 < 8)
      stage_g3(xb, wb, Xl0, Wl0, wave, lane, (kc + 2) * 64, scol);
    comp_g3(Xl1, Wl1, wr, wc, quad, l15, rsw, acc);
    VMCNT0; SBAR;
  }
#pragma unroll
  for (int s = 0; s < 4; ++s) {
    int row0 = tileM + wr * 64 + s * 16 + quad * 4;
#pragma unroll
    for (int nt = 0; nt < 4; ++nt) {
      int col = tileN + wc * 64 + nt * 16 + l15;
      float bv = (biasMode == 1) ? bias[col] : 0.0f;
#pragma unroll
      for (int r = 0; r < 4; ++r) {
        int row = row0 + r;
        float v = acc[s][nt][r] + bv;
        if (biasMode == 2) v += bias[(row / 196) * 512 + col];
        out[(size_t)row * N + col] = f2bf(v);
      }
    }
  }
}

// ---------------- MFMA attention: TWO blocks (by Q-strip half) per (b,h) ----------------
__global__ __launch_bounds__(256, 1) void k_attn2(const u16* __restrict__ qkv, u16* __restrict__ o_out) {
  const int blk = blockIdx.x;
  const int b = blk >> 4, h = (blk >> 1) & 7, half = blk & 1;
  const int sb = half * 8, se = half ? 13 : 8;
  __shared__ u16 Ks[208 * 72];
  __shared__ u16 Vt[64 * 232];
  __shared__ u16 Ps[4][16 * 232];
  const int tid = threadIdx.x;
  const int wave = tid >> 6, lane = tid & 63, quad = lane >> 4, l15 = lane & 15;
  const size_t base = (size_t)b * 196 * 1536 + (size_t)h * 64;

  for (int i = tid; i < 64 * 232 / 4; i += 256) ((unsigned long long*)Vt)[i] = 0ULL;
  for (int i = tid; i < 4 * 16 * 24; i += 256) {
    int w = i / 384, rem = i - w * 384;
    int r = rem / 24, c = rem - r * 24;
    Ps[w][r * 232 + 208 + c] = 0;
  }
  __syncthreads();

  for (int idx = tid; idx < 208 * 8; idx += 256) {
    int r = idx >> 3, c = (idx & 7) * 8;
    uint4 v = {0, 0, 0, 0};
    if (r < 196) v = *(const uint4*)&qkv[base + 512 + (size_t)r * 1536 + c];
    *(uint4*)&Ks[r * 72 + c] = v;
  }
  for (int idx = tid; idx < 196 * 8; idx += 256) {
    int p = idx >> 3, f0 = (idx & 7) * 8;
    uint4 v = *(const uint4*)&qkv[base + 1024 + (size_t)p * 1536 + f0];
    u16 t[8]; *(uint4*)t = v;
#pragma unroll
    for (int j = 0; j < 8; ++j) Vt[(f0 + j) * 232 + p] = t[j];
  }
  bf16x8 qz = {0, 0, 0, 0, 0, 0, 0, 0};
  bf16x8 qf[2][2];
#pragma unroll
  for (int i = 0; i < 2; ++i) {
    int s = sb + wave + i * 4;
    int row = s * 16 + l15;
#pragma unroll
    for (int c = 0; c < 2; ++c) {
      bf16x8 v = qz;
      if (s < se && row < 196)
        v = *(const bf16x8*)&qkv[base + (size_t)row * 1536 + c * 32 + quad * 8];
      qf[i][c] = v;
    }
  }
  __syncthreads();

  const f32x4 z = {0.f, 0.f, 0.f, 0.f};
  for (int i = 0; i < 2; ++i) {
    int s = sb + wave + i * 4;
    if (s >= se) break;
    f32x4 acc[13];
#pragma unroll
    for (int nt = 0; nt < 13; ++nt) acc[nt] = z;
#pragma unroll
    for (int c = 0; c < 2; ++c) {
      bf16x8 a = qf[i][c];
#pragma unroll
      for (int nt = 0; nt < 13; ++nt) {
        bf16x8 bfr = *(const bf16x8*)&Ks[(nt * 16 + l15) * 72 + c * 32 + quad * 8];
        acc[nt] = __builtin_amdgcn_mfma_f32_16x16x32_bf16(a, bfr, acc[nt], 0, 0, 0);
      }
    }
#pragma unroll
    for (int r = 0; r < 4; ++r) {
      float m = -3e38f;
#pragma unroll
      for (int nt = 0; nt < 13; ++nt) {
        float sv = acc[nt][r] * 0.125f;
        acc[nt][r] = sv;
        if (nt < 12 || l15 < 4) m = fmaxf(m, sv);
      }
#pragma unroll
      for (int off = 1; off < 16; off <<= 1) m = fmaxf(m, __shfl_xor(m, off));
      float ssum = 0.f;
#pragma unroll
      for (int nt = 0; nt < 13; ++nt) {
        float p = (nt < 12 || l15 < 4) ? __expf(acc[nt][r] - m) : 0.f;
        acc[nt][r] = p;
        ssum += p;
      }
#pragma unroll
      for (int off = 1; off < 16; off <<= 1) ssum += __shfl_xor(ssum, off);
      float is = 1.0f / ssum;
      int row = quad * 4 + r;
#pragma unroll
      for (int nt = 0; nt < 13; ++nt) {
        float v = acc[nt][r] * is;
        float vx = __shfl_xor(v, 1);
        if ((l15 & 1) == 0) {
          u32 pk = (u32)f2bf(v) | ((u32)f2bf(vx) << 16);
          *(u32*)&Ps[wave][row * 232 + nt * 16 + l15] = pk;
        }
      }
    }
    f32x4 oacc[4] = {z, z, z, z};
#pragma unroll
    for (int kc = 0; kc < 7; ++kc) {
      bf16x8 a = *(const bf16x8*)&Ps[wave][l15 * 232 + kc * 32 + quad * 8];
#pragma unroll
      for (int nt = 0; nt < 4; ++nt) {
        bf16x8 bfr = *(const bf16x8*)&Vt[(nt * 16 + l15) * 232 + kc * 32 + quad * 8];
        oacc[nt] = __builtin_amdgcn_mfma_f32_16x16x32_bf16(a, bfr, oacc[nt], 0, 0, 0);
      }
    }
#pragma unroll
    for (int nt = 0; nt < 4; ++nt) {
#pragma unroll
      for (int r = 0; r < 4; ++r) {
        int row = s * 16 + quad * 4 + r;
        if (row < 196)
          o_out[((size_t)b * 196 + row) * 512 + h * 64 + nt * 16 + l15] = f2bf(oacc[nt][r]);
      }
    }
  }
}

// ---------------- logits: C = QL(6272x512) @ KL(6272x512)^T, fused row/col max ----------------
// R6 decomposition (128x208 tile, wave strips {w,w+4}, acc[2][13]) with Q REMOVED
// from the LDS/staging path: each wave's 2 Q fragments per K-step are read
// DIRECTLY from global (QL is L3/L2-hot; rows reused 32x), prefetched one step
// ahead into 16 registers. Staging volume 21->13 KB/step, LDS reads 15->13 per
// wave/step, LDS 49.7KB -> 33.3KB. K staging + read swizzle + accumulation
// order unchanged (Q direct path needs no swizzle -> bit-identical results).
__global__ __launch_bounds__(256) void k_logits2(const u16* __restrict__ QL, const u16* __restrict__ KL,
                                                 u32* __restrict__ rowmax, u32* __restrict__ colmax) {
  int lin = blockIdx.y * 49 + blockIdx.x;
  lin = (lin & 7) * 196 + (lin >> 3);      // bijective: 1568 % 8 == 0
  const int bx = lin % 49, b = lin / 49;
  const int row0 = bx * 128;
  __shared__ u16 Kb0[208 * 32], Kb1[208 * 32];   // 13,312 B each
  __shared__ float colred[2][4 * 208];           //  6,656 B -> 33,280 B total
  const int tid = threadIdx.x;
  const int wave = tid >> 6, lane = tid & 63, quad = lane >> 4, l15 = lane & 15;
  const int scol = (((lane & 3) ^ ((lane >> 3) & 3)) << 3);  // K source swizzle (u16)
  const int co = ((quad ^ ((l15 >> 1) & 3)) << 3);           // K read swizzle (u16)
  const int r4 = lane >> 2;
  const int a0 = row0 / 196;
  const int lsplit = (a0 + 1) * 196 - row0; // local row where a increments (>=128 => single segment)
  const f32x4 z = {0.f, 0.f, 0.f, 0.f};
  f32x4 acc[2][13];
#pragma unroll
  for (int s = 0; s < 2; ++s)
#pragma unroll
    for (int nt = 0; nt < 13; ++nt) acc[s][nt] = z;
  const u16* kbase = KL + (size_t)b * 196 * 512;
  // per-lane Q source rows (no swizzle on the direct path)
  const u16* qrowA = QL + (size_t)(row0 + wave * 16 + l15) * 512 + quad * 8;
  const u16* qrowB = QL + (size_t)(row0 + (wave + 4) * 16 + l15) * 512 + quad * 8;

  auto STAGEK = [&](u16* Kb, int koff) {
#pragma unroll
    for (int i = 0; i < 4; ++i) {
      int s = wave + i * 4;
      if (s < 13) {
        int r = s * 16 + r4; if (r > 195) r = 195;  // clamp OOB rows (cols 196..207 masked later)
        gll16(kbase + (size_t)r * 512 + koff + scol, Kb + s * 512);
      }
    }
  };
  auto COMP = [&](const u16* Kb, bf16x8 af0, bf16x8 af1) {
    __builtin_amdgcn_s_setprio(1);
#pragma unroll
    for (int nt = 0; nt < 13; ++nt) {
      bf16x8 bf = *(const bf16x8*)&Kb[(nt * 16 + l15) * 32 + co];
      acc[0][nt] = __builtin_amdgcn_mfma_f32_16x16x32_bf16(af0, bf, acc[0][nt], 0, 0, 0);
      acc[1][nt] = __builtin_amdgcn_mfma_f32_16x16x32_bf16(af1, bf, acc[1][nt], 0, 0, 0);
    }
    __builtin_amdgcn_s_setprio(0);
  };

  STAGEK(Kb0, 0);
  bf16x8 qA0 = *(const bf16x8*)qrowA;
  bf16x8 qA1 = *(const bf16x8*)qrowB;
  VMCNT0; SBAR;
  for (int kc = 0; kc < 16; kc += 2) {
    STAGEK(Kb1, (kc + 1) * 32);
    bf16x8 qB0 = *(const bf16x8*)(qrowA + (kc + 1) * 32);
    bf16x8 qB1 = *(const bf16x8*)(qrowB + (kc + 1) * 32);
    COMP(Kb0, qA0, qA1);
    VMCNT0; SBAR;
    if (kc + 2 < 16) {
      STAGEK(Kb0, (kc + 2) * 32);
      qA0 = *(const bf16x8*)(qrowA + (kc + 2) * 32);
      qA1 = *(const bf16x8*)(qrowB + (kc + 2) * 32);
    }
    COMP(Kb1, qB0, qB1);
    VMCNT0; SBAR;
  }
  // ---- rowmax: complete within block (all 196 cols of b present) ----
#pragma unroll
  for (int s = 0; s < 2; ++s) {
#pragma unroll
    for (int r = 0; r < 4; ++r) {
      float m = -3e38f;
#pragma unroll
      for (int nt = 0; nt < 13; ++nt)
        if (nt < 12 || l15 < 4) m = fmaxf(m, acc[s][nt][r]);
#pragma unroll
      for (int off = 8; off > 0; off >>= 1) m = fmaxf(m, __shfl_xor(m, off, 16));
      if (l15 == 0) {
        int lr = (wave + s * 4) * 16 + quad * 4 + r;
        int aa = a0, ll = row0 - a0 * 196 + lr;
        if (ll >= 196) { aa += 1; ll -= 196; }
        atomicMax(&rowmax[((size_t)aa * 32 + b) * 196 + ll], encf(m));
      }
    }
  }
  // ---- colmax: segment rows by a before cross-quad shuffles ----
#pragma unroll
  for (int nt = 0; nt < 13; ++nt) {
    float cm0 = -3e38f, cm1 = -3e38f;
#pragma unroll
    for (int s = 0; s < 2; ++s)
#pragma unroll
      for (int r = 0; r < 4; ++r) {
        int lr = (wave + s * 4) * 16 + quad * 4 + r;
        float v = acc[s][nt][r];
        if (lr < lsplit) cm0 = fmaxf(cm0, v); else cm1 = fmaxf(cm1, v);
      }
    cm0 = fmaxf(cm0, __shfl_xor(cm0, 16)); cm0 = fmaxf(cm0, __shfl_xor(cm0, 32));
    cm1 = fmaxf(cm1, __shfl_xor(cm1, 16)); cm1 = fmaxf(cm1, __shfl_xor(cm1, 32));
    if (quad == 0) {
      colred[0][wave * 208 + nt * 16 + l15] = cm0;
      colred[1][wave * 208 + nt * 16 + l15] = cm1;
    }
  }
  __syncthreads();
  for (int c = tid; c < 196; c += 256) {
    float m0 = fmaxf(fmaxf(colred[0][c], colred[0][208 + c]), fmaxf(colred[0][416 + c], colred[0][624 + c]));
    atomicMax(&colmax[((size_t)a0 * 32 + b) * 196 + c], encf(m0));
    if (lsplit < 128) {
      float m1 = fmaxf(fmaxf(colred[1][c], colred[1][208 + c]), fmaxf(colred[1][416 + c], colred[1][624 + c]));
      atomicMax(&colmax[((size_t)(a0 + 1) * 32 + b) * 196 + c], encf(m1));
    }
  }
}

// ---------------- S reduction: 256 blocks, one S entry per wave ----------------
__global__ __launch_bounds__(256) void k_sred(const u32* __restrict__ maxbuf, float* __restrict__ Sws) {
  int wave = threadIdx.x >> 6, lane = threadIdx.x & 63;
  int p = blockIdx.x * 4 + wave;  // pair index 0..1023
  const u32* rp = maxbuf + (size_t)p * 196;
  const u32* cp = maxbuf + 200704 + (size_t)p * 196;
  float s = 0.f;
  for (int i = lane; i < 196; i += 64) s += decf(rp[i]) + decf(cp[i]);
#pragma unroll
  for (int off = 1; off < 64; off <<= 1) s += __shfl_xor(s, off);
  if (lane == 0) Sws[p] = s;
}

// ---------------- final: S matrix + symmetric cross-entropy (4KB read) ----------------
__global__ __launch_bounds__(1024) void k_final(const float* __restrict__ Sws,
                                                const float* __restrict__ logit_scale, float* __restrict__ out) {
  __shared__ float S[1024];
  __shared__ float terms[64];
  int tid = threadIdx.x; // == pair
  float sc = 0.5f * __expf(logit_scale[0]);
  S[tid] = sc * Sws[tid] * (1.0f / 196.0f);
  __syncthreads();
  if (tid < 64) {
    int aa = tid & 31;
    bool rowMode = tid < 32;
    float mx = -3e38f;
    for (int j = 0; j < 32; ++j) {
      float v = rowMode ? S[aa * 32 + j] : S[j * 32 + aa];
      mx = fmaxf(mx, v);
    }
    float se = 0.f;
    for (int j = 0; j < 32; ++j) {
      float v = rowMode ? S[aa * 32 + j] : S[j * 32 + aa];
      se += __expf(v - mx);
    }
    terms[tid] = S[aa * 33] - (mx + logf(se));
  }
  __syncthreads();
  if (tid == 0) {
    float s2 = 0.f;
    for (int i = 0; i < 64; ++i) s2 += terms[i];
    out[0] = -s2 * (1.0f / 64.0f);
  }
}

// ---------------- host ----------------
extern "C" void kernel_launch(void* const* d_in, const int* in_sizes, int n_in,
                              void* d_out, int out_size, void* d_ws, size_t ws_size,
                              hipStream_t stream) {
  const float* bef       = (const float*)d_in[0];
  const float* sent      = (const float*)d_in[1];
  const float* aft       = (const float*)d_in[2];
  const float* masks     = (const float*)d_in[3];
  const float* conv1_w   = (const float*)d_in[4];
  const float* conv1_b   = (const float*)d_in[5];
  const float* in_proj_w = (const float*)d_in[6];
  const float* out_proj_w= (const float*)d_in[7];
  const float* conv2_w   = (const float*)d_in[8];
  const float* conv2_b   = (const float*)d_in[9];
  const float* q_w       = (const float*)d_in[10];
  const float* q_b       = (const float*)d_in[11];
  const float* k_w       = (const float*)d_in[12];
  const float* k_b       = (const float*)d_in[13];
  const float* logit_scale = (const float*)d_in[14];
  float* out = (float*)d_out;

  char* ws = (char*)d_ws;
  size_t off = 0;
  auto alloc = [&](size_t bytes) -> char* {
    char* p = ws + off;
    off += (bytes + 255) & ~(size_t)255;
    return p;
  };
  const size_t MROWS = 32 * 196; // 6272
  u16* bef16    = (u16*)alloc(MROWS * 512 * 2);
  u16* aft16    = (u16*)alloc(MROWS * 512 * 2);
  u16* w1a16    = (u16*)alloc(512 * 512 * 2);
  u16* inproj16 = (u16*)alloc(1536 * 512 * 2);
  u16* kw16     = (u16*)alloc(512 * 512 * 2);
  u16* qw16     = (u16*)alloc(512 * 512 * 2);
  u16* wcT16    = (u16*)alloc(512 * 512 * 2);
  u16* woT16    = (u16*)alloc(512 * 512 * 2);
  u16* wt16     = (u16*)alloc(512 * 512 * 2);
  u16* wcomb16  = (u16*)alloc(512 * 512 * 2);
  float* biasb  = (float*)alloc(32 * 512 * 4);
  float* biasq  = (float*)alloc(512 * 4);
  u16* v116     = (u16*)alloc(MROWS * 512 * 2);
  u16* qkv16    = (u16*)alloc(MROWS * 1536 * 2);
  u16* oattn16  = (u16*)alloc(MROWS * 512 * 2);
  u16* QL16     = (u16*)alloc(MROWS * 512 * 2);
  u16* KL16     = (u16*)alloc(MROWS * 512 * 2);
  u32* maxbuf   = (u32*)alloc(2 * 32 * 32 * 196 * 4); // rowmax | colmax
  float* Sws    = (float*)alloc(1024 * 4);
  u32* rowmax   = maxbuf;
  u32* colmax   = maxbuf + 32 * 32 * 196;

  // fused prep: all casts, transposes, sentbias, biasq, maxbuf init (one launch)
  k_prep<<<4842, 256, 0, stream>>>(bef, aft, sent, masks, conv1_w, conv1_b,
                                   in_proj_w, out_proj_w, conv2_w, conv2_b,
                                   q_w, q_b, k_w,
                                   bef16, aft16, inproj16, kw16, qw16,
                                   w1a16, wcT16, woT16, biasb, biasq,
                                   (uint4*)maxbuf);
  // [v1 = bef @ W1a^T + biasb[b]]  ||  [wt = Wq @ WcT]
  k_gemm3d<<<212, 256, 0, stream>>>(bef16, w1a16, v116, biasb, 49, 512, 2, 196,
                                    qw16, wcT16, wt16, nullptr, 4, 512, 0);
  // [qkv = v1 @ in_proj^T]  ||  [wcomb = wt @ WoT]
  k_gemm3d<<<604, 256, 0, stream>>>(v116, inproj16, qkv16, nullptr, 49, 1536, 0, 588,
                                    wt16, woT16, wcomb16, nullptr, 4, 512, 0);
  // attention (MFMA), 2 blocks per (b,h)
  k_attn2<<<512, 256, 0, stream>>>(qkv16, oattn16);
  // [QL = o_attn @ Wcomb^T + biasq]  ||  [KL = aft @ k_w^T + k_b]
  k_gemm3d<<<392, 256, 0, stream>>>(oattn16, wcomb16, QL16, biasq, 49, 512, 1, 196,
                                    aft16, kw16, KL16, k_b, 49, 512, 1);
  // logits reductions: Q-from-global, K-only LDS dbuf
  k_logits2<<<dim3(49, 32), 256, 0, stream>>>(QL16, KL16, rowmax, colmax);
  // S reduction + final loss
  k_sred<<<256, 256, 0, stream>>>(maxbuf, Sws);
  k_final<<<1, 1024, 0, stream>>>(Sws, logit_scale, out);
}

// Round 11
// 331.595 us; speedup vs baseline: 1.2392x; 1.2392x over previous
//
#include <hip/hip_runtime.h>

// B=32, LV=196, LT=40, D=512, H=8, DH=64

typedef unsigned int u32;
typedef unsigned short u16;
typedef __attribute__((ext_vector_type(8))) short bf16x8;
typedef __attribute__((ext_vector_type(4))) float f32x4;

#define DEV __device__ __forceinline__

DEV u16 f2bf(float f) {
  u32 u = __builtin_bit_cast(u32, f);
  u = (u + 0x7FFFu + ((u >> 16) & 1u)) >> 16;
  return (u16)u;
}
DEV float bf2f(u16 h) { u32 u = ((u32)h) << 16; return __builtin_bit_cast(float, u); }
// monotonic float<->u32 encoding for atomicMax on floats (enc(x)>enc(y) iff x>y)
DEV u32 encf(float f) { u32 u = __builtin_bit_cast(u32, f); return (u & 0x80000000u) ? ~u : (u | 0x80000000u); }
DEV float decf(u32 e) { u32 u = (e & 0x80000000u) ? (e & 0x7FFFFFFFu) : ~e; return __builtin_bit_cast(float, u); }

// async global->LDS, 16B per lane. LDS dest = wave-uniform base + lane*16 (HW).
// Global src is PER-LANE: pre-swizzled so the swizzled ds_read is conflict-free.
DEV void gll16(const u16* g, u16* l) {
  __builtin_amdgcn_global_load_lds(
      (const __attribute__((address_space(1))) void*)g,
      (__attribute__((address_space(3))) void*)l, 16, 0, 0);
}

#define VMCNT0 asm volatile("s_waitcnt vmcnt(0)" ::: "memory")
#define SBAR __builtin_amdgcn_s_barrier()

// ---------------- fused prep: all casts + transposes + sentbias + biasq + init ----------------
DEV void cast8(const float* __restrict__ in, u16* __restrict__ out, int i) {
  const float4* p = (const float4*)in + (size_t)i * 2;
  float4 a = p[0], b = p[1];
  u16 t[8] = {f2bf(a.x), f2bf(a.y), f2bf(a.z), f2bf(a.w),
              f2bf(b.x), f2bf(b.y), f2bf(b.z), f2bf(b.w)};
  *(uint4*)(out + (size_t)i * 8) = *(uint4*)t;
}

DEV void tcast(const float* __restrict__ in, u16* __restrict__ out, int t, int tid, float* sm) {
  int bx = t & 15, by = t >> 4;
  int tx = tid & 31, ty = tid >> 5;
  float (*tt)[33] = (float(*)[33])sm;
  for (int i = ty; i < 32; i += 8) tt[i][tx] = in[(size_t)(by * 32 + i) * 512 + bx * 32 + tx];
  __syncthreads();
  for (int i = ty; i < 32; i += 8) out[(size_t)(bx * 32 + i) * 512 + by * 32 + tx] = f2bf(tt[tx][i]);
}

__global__ __launch_bounds__(256) void k_prep(
    const float* __restrict__ bef, const float* __restrict__ aft,
    const float* __restrict__ sent, const float* __restrict__ masks,
    const float* __restrict__ conv1_w, const float* __restrict__ conv1_b,
    const float* __restrict__ in_proj_w, const float* __restrict__ out_proj_w,
    const float* __restrict__ conv2_w, const float* __restrict__ conv2_b,
    const float* __restrict__ q_w, const float* __restrict__ q_b,
    const float* __restrict__ k_w,
    u16* __restrict__ bef16, u16* __restrict__ aft16,
    u16* __restrict__ inproj16, u16* __restrict__ kw16, u16* __restrict__ qw16,
    u16* __restrict__ w1a16, u16* __restrict__ wcT16, u16* __restrict__ woT16,
    float* __restrict__ biasb, float* __restrict__ biasq,
    uint4* __restrict__ maxbuf) {
  __shared__ float smemf[1056];
  const int blk = blockIdx.x, tid = threadIdx.x;
  if (blk < 32) {
    // sentbias: masked text mean -> conv1 text-half bias, b = blk
    int b = blk;
    float* sm = smemf;
    for (int d = tid; d < 512; d += 256) {
      float s = 0.f;
#pragma unroll 8
      for (int t = 0; t < 40; ++t) s += sent[(size_t)b * 40 * 512 + (size_t)t * 512 + d] * masks[b * 40 + t];
      sm[d] = s * (1.0f / 40.0f);
    }
    __syncthreads();
    for (int o = tid; o < 512; o += 256) {
      const float* wr = conv1_w + (size_t)o * 1024 + 512;
      float acc = conv1_b[o];
#pragma unroll 8
      for (int c = 0; c < 512; ++c) acc += sm[c] * wr[c];
      biasb[b * 512 + o] = acc;
    }
  } else if (blk < 424) {
    // init maxbuf: 392 blocks * 256 = 100352 uint4
    maxbuf[(size_t)(blk - 32) * 256 + tid] = (uint4){0u, 0u, 0u, 0u};
  } else if (blk < 426) {
    // biasq
    int j = (blk - 424) * 256 + tid;
    if (j < 512) {
      const float* wr = q_w + (size_t)j * 512;
      float acc = q_b[j];
#pragma unroll 8
      for (int d = 0; d < 512; ++d) acc += wr[d] * conv2_b[d];
      biasq[j] = acc;
    }
  } else if (blk < 1994) {
    cast8(bef, bef16, (blk - 426) * 256 + tid);       // 401408 groups
  } else if (blk < 3562) {
    cast8(aft, aft16, (blk - 1994) * 256 + tid);
  } else if (blk < 3946) {
    cast8(in_proj_w, inproj16, (blk - 3562) * 256 + tid);
  } else if (blk < 4074) {
    cast8(k_w, kw16, (blk - 3946) * 256 + tid);
  } else if (blk < 4202) {
    cast8(q_w, qw16, (blk - 4074) * 256 + tid);
  } else if (blk < 4330) {
    // conv1a: image half of conv1_w
    int i = (blk - 4202) * 256 + tid;
    int o = i >> 6, c0 = (i & 63) * 8;
    const float* p = conv1_w + (size_t)o * 1024 + c0;
    u16 t[8];
#pragma unroll
    for (int j = 0; j < 8; ++j) t[j] = f2bf(p[j]);
    *(uint4*)(w1a16 + (size_t)o * 512 + c0) = *(uint4*)t;
  } else if (blk < 4586) {
    tcast(conv2_w, wcT16, blk - 4330, tid, smemf);
  } else {
    tcast(out_proj_w, woT16, blk - 4586, tid, smemf);
  }
}

// ---------------- bf16 MFMA GEMM, m97-style 128x128 tile: C = X(MxK) @ W(NxK)^T, K=512 ----------------
// 4 waves in 2x2 quadrants: wave (wr,wc) owns 64x64 (acc[4][4] = 64 VGPR).
// Per kk: 8 ds_read_b128 : 16 MFMA (0.5 ratio). Staging via gload_lds (zero
// VGPRs) + both-sides swizzle; 2-phase dbuf template. Dual-job launch.
DEV void stage_g3(const u16* __restrict__ xb, const u16* __restrict__ wb,
                  u16* Xb, u16* Wb, int wave, int lane, int koff, int scol) {
  int r8 = lane >> 3;
#pragma unroll
  for (int i = 0; i < 8; ++i) {
    int s = wave + i * 4;
    if (s < 16) gll16(xb + (size_t)(s * 8 + r8) * 512 + koff + scol, Xb + s * 512);
    else        gll16(wb + (size_t)((s - 16) * 8 + r8) * 512 + koff + scol, Wb + (s - 16) * 512);
  }
}

DEV void comp_g3(const u16* Xb, const u16* Wb, int wr, int wc, int quad, int l15, int rsw,
                 f32x4 (&acc)[4][4]) {
#pragma unroll
  for (int kk = 0; kk < 64; kk += 32) {
    int co = (kk | (quad << 3)) ^ rsw;
    bf16x8 af[4];
#pragma unroll
    for (int s = 0; s < 4; ++s)
      af[s] = *(const bf16x8*)&Xb[(wr * 64 + s * 16 + l15) * 64 + co];
#pragma unroll
    for (int nt = 0; nt < 4; ++nt) {
      bf16x8 b = *(const bf16x8*)&Wb[(wc * 64 + nt * 16 + l15) * 64 + co];
#pragma unroll
      for (int s = 0; s < 4; ++s)
        acc[s][nt] = __builtin_amdgcn_mfma_f32_16x16x32_bf16(af[s], b, acc[s][nt], 0, 0, 0);
    }
  }
}

// biasMode: 0 none, 1 per-col bias[col], 2 per-batch-row bias[(row/196)*512+col]
__global__ __launch_bounds__(256) void k_gemm3d(
    const u16* __restrict__ X1, const u16* __restrict__ W1, u16* __restrict__ o1,
    const float* __restrict__ b1, int nbx1, int N1, int m1, int nblk1,
    const u16* __restrict__ X2, const u16* __restrict__ W2, u16* __restrict__ o2,
    const float* __restrict__ b2, int nbx2, int N2, int m2) {
  __shared__ u16 Xl0[128 * 64], Xl1[128 * 64];
  __shared__ u16 Wl0[128 * 64], Wl1[128 * 64];
  int g = blockIdx.x;
  const u16 *X, *W; u16* out; const float* bias; int N, biasMode, bx, by;
  if (g < nblk1) {
    X = X1; W = W1; out = o1; bias = b1; N = N1; biasMode = m1;
    bx = g % nbx1; by = g / nbx1;
  } else {
    g -= nblk1;
    X = X2; W = W2; out = o2; bias = b2; N = N2; biasMode = m2;
    bx = g % nbx2; by = g / nbx2;
  }
  int tid = threadIdx.x;
  int tileM = bx * 128, tileN = by * 128;
  int wave = tid >> 6, lane = tid & 63, quad = lane >> 4, l15 = lane & 15;
  int wr = wave >> 1, wc = wave & 1;
  const int rsw = (l15 & 7) << 3;                              // read-side swizzle (u16 units)
  const int scol = (((lane & 7) ^ ((lane >> 3) & 7)) << 3);    // source-side swizzle (u16 units)
  f32x4 z = {0.f, 0.f, 0.f, 0.f};
  f32x4 acc[4][4];
#pragma unroll
  for (int s = 0; s < 4; ++s)
#pragma unroll
    for (int nt = 0; nt < 4; ++nt) acc[s][nt] = z;
  const u16* xb = X + (size_t)tileM * 512;
  const u16* wb = W + (size_t)tileN * 512;

  stage_g3(xb, wb, Xl0, Wl0, wave, lane, 0, scol);
  VMCNT0; SBAR;
#pragma unroll
  for (int kc = 0; kc < 8; kc += 2) {
    stage_g3(xb, wb, Xl1, Wl1, wave, lane, (kc + 1) * 64, scol);
    comp_g3(Xl0, Wl0, wr, wc, quad, l15, rsw, acc);
    VMCNT0; SBAR;
    if (kc + 2 < 8)
      stage_g3(xb, wb, Xl0, Wl0, wave, lane, (kc + 2) * 64, scol);
    comp_g3(Xl1, Wl1, wr, wc, quad, l15, rsw, acc);
    VMCNT0; SBAR;
  }
#pragma unroll
  for (int s = 0; s < 4; ++s) {
    int row0 = tileM + wr * 64 + s * 16 + quad * 4;
#pragma unroll
    for (int nt = 0; nt < 4; ++nt) {
      int col = tileN + wc * 64 + nt * 16 + l15;
      float bv = (biasMode == 1) ? bias[col] : 0.0f;
#pragma unroll
      for (int r = 0; r < 4; ++r) {
        int row = row0 + r;
        float v = acc[s][nt][r] + bv;
        if (biasMode == 2) v += bias[(row / 196) * 512 + col];
        out[(size_t)row * N + col] = f2bf(v);
      }
    }
  }
}

// ---------------- MFMA attention: TWO blocks (by Q-strip half) per (b,h) ----------------
__global__ __launch_bounds__(256, 1) void k_attn2(const u16* __restrict__ qkv, u16* __restrict__ o_out) {
  const int blk = blockIdx.x;
  const int b = blk >> 4, h = (blk >> 1) & 7, half = blk & 1;
  const int sb = half * 8, se = half ? 13 : 8;
  __shared__ u16 Ks[208 * 72];
  __shared__ u16 Vt[64 * 232];
  __shared__ u16 Ps[4][16 * 232];
  const int tid = threadIdx.x;
  const int wave = tid >> 6, lane = tid & 63, quad = lane >> 4, l15 = lane & 15;
  const size_t base = (size_t)b * 196 * 1536 + (size_t)h * 64;

  for (int i = tid; i < 64 * 232 / 4; i += 256) ((unsigned long long*)Vt)[i] = 0ULL;
  for (int i = tid; i < 4 * 16 * 24; i += 256) {
    int w = i / 384, rem = i - w * 384;
    int r = rem / 24, c = rem - r * 24;
    Ps[w][r * 232 + 208 + c] = 0;
  }
  __syncthreads();

  for (int idx = tid; idx < 208 * 8; idx += 256) {
    int r = idx >> 3, c = (idx & 7) * 8;
    uint4 v = {0, 0, 0, 0};
    if (r < 196) v = *(const uint4*)&qkv[base + 512 + (size_t)r * 1536 + c];
    *(uint4*)&Ks[r * 72 + c] = v;
  }
  for (int idx = tid; idx < 196 * 8; idx += 256) {
    int p = idx >> 3, f0 = (idx & 7) * 8;
    uint4 v = *(const uint4*)&qkv[base + 1024 + (size_t)p * 1536 + f0];
    u16 t[8]; *(uint4*)t = v;
#pragma unroll
    for (int j = 0; j < 8; ++j) Vt[(f0 + j) * 232 + p] = t[j];
  }
  bf16x8 qz = {0, 0, 0, 0, 0, 0, 0, 0};
  bf16x8 qf[2][2];
#pragma unroll
  for (int i = 0; i < 2; ++i) {
    int s = sb + wave + i * 4;
    int row = s * 16 + l15;
#pragma unroll
    for (int c = 0; c < 2; ++c) {
      bf16x8 v = qz;
      if (s < se && row < 196)
        v = *(const bf16x8*)&qkv[base + (size_t)row * 1536 + c * 32 + quad * 8];
      qf[i][c] = v;
    }
  }
  __syncthreads();

  const f32x4 z = {0.f, 0.f, 0.f, 0.f};
  for (int i = 0; i < 2; ++i) {
    int s = sb + wave + i * 4;
    if (s >= se) break;
    f32x4 acc[13];
#pragma unroll
    for (int nt = 0; nt < 13; ++nt) acc[nt] = z;
#pragma unroll
    for (int c = 0; c < 2; ++c) {
      bf16x8 a = qf[i][c];
#pragma unroll
      for (int nt = 0; nt < 13; ++nt) {
        bf16x8 bfr = *(const bf16x8*)&Ks[(nt * 16 + l15) * 72 + c * 32 + quad * 8];
        acc[nt] = __builtin_amdgcn_mfma_f32_16x16x32_bf16(a, bfr, acc[nt], 0, 0, 0);
      }
    }
#pragma unroll
    for (int r = 0; r < 4; ++r) {
      float m = -3e38f;
#pragma unroll
      for (int nt = 0; nt < 13; ++nt) {
        float sv = acc[nt][r] * 0.125f;
        acc[nt][r] = sv;
        if (nt < 12 || l15 < 4) m = fmaxf(m, sv);
      }
#pragma unroll
      for (int off = 1; off < 16; off <<= 1) m = fmaxf(m, __shfl_xor(m, off));
      float ssum = 0.f;
#pragma unroll
      for (int nt = 0; nt < 13; ++nt) {
        float p = (nt < 12 || l15 < 4) ? __expf(acc[nt][r] - m) : 0.f;
        acc[nt][r] = p;
        ssum += p;
      }
#pragma unroll
      for (int off = 1; off < 16; off <<= 1) ssum += __shfl_xor(ssum, off);
      float is = 1.0f / ssum;
      int row = quad * 4 + r;
#pragma unroll
      for (int nt = 0; nt < 13; ++nt) {
        float v = acc[nt][r] * is;
        float vx = __shfl_xor(v, 1);
        if ((l15 & 1) == 0) {
          u32 pk = (u32)f2bf(v) | ((u32)f2bf(vx) << 16);
          *(u32*)&Ps[wave][row * 232 + nt * 16 + l15] = pk;
        }
      }
    }
    f32x4 oacc[4] = {z, z, z, z};
#pragma unroll
    for (int kc = 0; kc < 7; ++kc) {
      bf16x8 a = *(const bf16x8*)&Ps[wave][l15 * 232 + kc * 32 + quad * 8];
#pragma unroll
      for (int nt = 0; nt < 4; ++nt) {
        bf16x8 bfr = *(const bf16x8*)&Vt[(nt * 16 + l15) * 232 + kc * 32 + quad * 8];
        oacc[nt] = __builtin_amdgcn_mfma_f32_16x16x32_bf16(a, bfr, oacc[nt], 0, 0, 0);
      }
    }
#pragma unroll
    for (int nt = 0; nt < 4; ++nt) {
#pragma unroll
      for (int r = 0; r < 4; ++r) {
        int row = s * 16 + quad * 4 + r;
        if (row < 196)
          o_out[((size_t)b * 196 + row) * 512 + h * 64 + nt * 16 + l15] = f2bf(oacc[nt][r]);
      }
    }
  }
}

// ---------------- logits: C = QL(6272x512) @ KL(6272x512)^T, fused row/col max ----------------
// Best-measured structure (R5/R6, 75-77us): 128x208 tile, wave strips {w,w+4},
// acc[2][13] (the proven 104-reg shape), gload_lds + both-sides swizzle
// (0 conflicts), TRIPLE-buffered 2-ahead pipeline with per-wave counted vmcnt,
// setprio around the MFMA cluster, bijective XCD remap. FROZEN: seven
// alternative structures (R4/R7/R8/R9/R10 variants) all landed 75-135us.
DEV void stage_lg(const u16* __restrict__ qbase, const u16* __restrict__ kbase,
                  u16* Qb, u16* Kb, int wave, int lane, int koff, int scol) {
  int r4 = lane >> 2;
#pragma unroll
  for (int i = 0; i < 6; ++i) {
    int s = wave + i * 4;
    if (s < 8) {
      gll16(qbase + (size_t)(s * 16 + r4) * 512 + koff + scol, Qb + s * 512);
    } else if (s < 21) {
      int j = s - 8;
      int r = j * 16 + r4; if (r > 195) r = 195;  // clamp OOB rows (cols 196..207 masked later)
      gll16(kbase + (size_t)r * 512 + koff + scol, Kb + j * 512);
    }
  }
}

DEV void comp_lg(const u16* Qb, const u16* Kb, int wave, int l15, int co, f32x4 (&acc)[2][13]) {
  bf16x8 af0 = *(const bf16x8*)&Qb[(wave * 16 + l15) * 32 + co];
  bf16x8 af1 = *(const bf16x8*)&Qb[((wave + 4) * 16 + l15) * 32 + co];
  __builtin_amdgcn_s_setprio(1);
#pragma unroll
  for (int nt = 0; nt < 13; ++nt) {
    bf16x8 b = *(const bf16x8*)&Kb[(nt * 16 + l15) * 32 + co];
    acc[0][nt] = __builtin_amdgcn_mfma_f32_16x16x32_bf16(af0, b, acc[0][nt], 0, 0, 0);
    acc[1][nt] = __builtin_amdgcn_mfma_f32_16x16x32_bf16(af1, b, acc[1][nt], 0, 0, 0);
  }
  __builtin_amdgcn_s_setprio(0);
}

// per-wave counted wait: allow the in-flight stage (W loads) of tile t+1 to
// remain outstanding while guaranteeing tile t's loads have landed.
#define WAIT_W() do { \
    if (wave == 0) asm volatile("s_waitcnt vmcnt(6)" ::: "memory"); \
    else           asm volatile("s_waitcnt vmcnt(5)" ::: "memory"); \
  } while (0)

__global__ __launch_bounds__(256) void k_logits2(const u16* __restrict__ QL, const u16* __restrict__ KL,
                                                 u32* __restrict__ rowmax, u32* __restrict__ colmax) {
  int lin = blockIdx.y * 49 + blockIdx.x;
  lin = (lin & 7) * 196 + (lin >> 3);      // bijective: 1568 % 8 == 0
  const int bx = lin % 49, b = lin / 49;
  const int row0 = bx * 128;
  __shared__ u16 Qb0[128 * 32], Qb1[128 * 32], Qb2[128 * 32];  // 8,192 B each
  __shared__ u16 Kb0[208 * 32], Kb1[208 * 32], Kb2[208 * 32];  // 13,312 B each
  __shared__ float colred[2][4 * 208];                         //  6,656 B -> 71,168 B total
  const int tid = threadIdx.x;
  const int wave = tid >> 6, lane = tid & 63, quad = lane >> 4, l15 = lane & 15;
  const int scol = (((lane & 3) ^ ((lane >> 3) & 3)) << 3);  // source swizzle (u16)
  const int co = ((quad ^ ((l15 >> 1) & 3)) << 3);           // read swizzle (u16)
  const int a0 = row0 / 196;
  const int lsplit = (a0 + 1) * 196 - row0; // local row where a increments (>=128 => single segment)
  const f32x4 z = {0.f, 0.f, 0.f, 0.f};
  f32x4 acc[2][13];
#pragma unroll
  for (int s = 0; s < 2; ++s)
#pragma unroll
    for (int nt = 0; nt < 13; ++nt) acc[s][nt] = z;
  const u16* qbase = QL + (size_t)row0 * 512;
  const u16* kbase = KL + (size_t)b * 196 * 512;

  u16 *qa = Qb0, *qb = Qb1, *qc = Qb2;
  u16 *ka = Kb0, *kb = Kb1, *kc = Kb2;
  stage_lg(qbase, kbase, qa, ka, wave, lane, 0, scol);
  stage_lg(qbase, kbase, qb, kb, wave, lane, 32, scol);
  for (int t = 0; t < 14; ++t) {
    WAIT_W();            // tile t landed (t+1's W loads may stay in flight)
    SBAR;                // all waves: tile t complete, buf[(t+2)%3] free
    stage_lg(qbase, kbase, qc, kc, wave, lane, (t + 2) * 32, scol);
    comp_lg(qa, ka, wave, l15, co, acc);
    u16* tq = qa; qa = qb; qb = qc; qc = tq;
    u16* tk = ka; ka = kb; kb = kc; kc = tk;
  }
  WAIT_W(); SBAR;
  comp_lg(qa, ka, wave, l15, co, acc);
  { u16* tq = qa; qa = qb; qb = qc; qc = tq;
    u16* tk = ka; ka = kb; kb = kc; kc = tk; }
  VMCNT0; SBAR;
  comp_lg(qa, ka, wave, l15, co, acc);

  // ---- rowmax: complete within block (all 196 cols of b present) ----
#pragma unroll
  for (int s = 0; s < 2; ++s) {
#pragma unroll
    for (int r = 0; r < 4; ++r) {
      float m = -3e38f;
#pragma unroll
      for (int nt = 0; nt < 13; ++nt)
        if (nt < 12 || l15 < 4) m = fmaxf(m, acc[s][nt][r]);
#pragma unroll
      for (int off = 8; off > 0; off >>= 1) m = fmaxf(m, __shfl_xor(m, off, 16));
      if (l15 == 0) {
        int lr = (wave + s * 4) * 16 + quad * 4 + r;
        int aa = a0, ll = row0 - a0 * 196 + lr;
        if (ll >= 196) { aa += 1; ll -= 196; }
        atomicMax(&rowmax[((size_t)aa * 32 + b) * 196 + ll], encf(m));
      }
    }
  }
  // ---- colmax: segment rows by a before cross-quad shuffles ----
#pragma unroll
  for (int nt = 0; nt < 13; ++nt) {
    float cm0 = -3e38f, cm1 = -3e38f;
#pragma unroll
    for (int s = 0; s < 2; ++s)
#pragma unroll
      for (int r = 0; r < 4; ++r) {
        int lr = (wave + s * 4) * 16 + quad * 4 + r;
        float v = acc[s][nt][r];
        if (lr < lsplit) cm0 = fmaxf(cm0, v); else cm1 = fmaxf(cm1, v);
      }
    cm0 = fmaxf(cm0, __shfl_xor(cm0, 16)); cm0 = fmaxf(cm0, __shfl_xor(cm0, 32));
    cm1 = fmaxf(cm1, __shfl_xor(cm1, 16)); cm1 = fmaxf(cm1, __shfl_xor(cm1, 32));
    if (quad == 0) {
      colred[0][wave * 208 + nt * 16 + l15] = cm0;
      colred[1][wave * 208 + nt * 16 + l15] = cm1;
    }
  }
  __syncthreads();
  for (int c = tid; c < 196; c += 256) {
    float m0 = fmaxf(fmaxf(colred[0][c], colred[0][208 + c]), fmaxf(colred[0][416 + c], colred[0][624 + c]));
    atomicMax(&colmax[((size_t)a0 * 32 + b) * 196 + c], encf(m0));
    if (lsplit < 128) {
      float m1 = fmaxf(fmaxf(colred[1][c], colred[1][208 + c]), fmaxf(colred[1][416 + c], colred[1][624 + c]));
      atomicMax(&colmax[((size_t)(a0 + 1) * 32 + b) * 196 + c], encf(m1));
    }
  }
}

// ---------------- S reduction: 256 blocks, one S entry per wave ----------------
__global__ __launch_bounds__(256) void k_sred(const u32* __restrict__ maxbuf, float* __restrict__ Sws) {
  int wave = threadIdx.x >> 6, lane = threadIdx.x & 63;
  int p = blockIdx.x * 4 + wave;  // pair index 0..1023
  const u32* rp = maxbuf + (size_t)p * 196;
  const u32* cp = maxbuf + 200704 + (size_t)p * 196;
  float s = 0.f;
  for (int i = lane; i < 196; i += 64) s += decf(rp[i]) + decf(cp[i]);
#pragma unroll
  for (int off = 1; off < 64; off <<= 1) s += __shfl_xor(s, off);
  if (lane == 0) Sws[p] = s;
}

// ---------------- final: S matrix + symmetric cross-entropy (4KB read) ----------------
__global__ __launch_bounds__(1024) void k_final(const float* __restrict__ Sws,
                                                const float* __restrict__ logit_scale, float* __restrict__ out) {
  __shared__ float S[1024];
  __shared__ float terms[64];
  int tid = threadIdx.x; // == pair
  float sc = 0.5f * __expf(logit_scale[0]);
  S[tid] = sc * Sws[tid] * (1.0f / 196.0f);
  __syncthreads();
  if (tid < 64) {
    int aa = tid & 31;
    bool rowMode = tid < 32;
    float mx = -3e38f;
    for (int j = 0; j < 32; ++j) {
      float v = rowMode ? S[aa * 32 + j] : S[j * 32 + aa];
      mx = fmaxf(mx, v);
    }
    float se = 0.f;
    for (int j = 0; j < 32; ++j) {
      float v = rowMode ? S[aa * 32 + j] : S[j * 32 + aa];
      se += __expf(v - mx);
    }
    terms[tid] = S[aa * 33] - (mx + logf(se));
  }
  __syncthreads();
  if (tid == 0) {
    float s2 = 0.f;
    for (int i = 0; i < 64; ++i) s2 += terms[i];
    out[0] = -s2 * (1.0f / 64.0f);
  }
}

// ---------------- host ----------------
extern "C" void kernel_launch(void* const* d_in, const int* in_sizes, int n_in,
                              void* d_out, int out_size, void* d_ws, size_t ws_size,
                              hipStream_t stream) {
  const float* bef       = (const float*)d_in[0];
  const float* sent      = (const float*)d_in[1];
  const float* aft       = (const float*)d_in[2];
  const float* masks     = (const float*)d_in[3];
  const float* conv1_w   = (const float*)d_in[4];
  const float* conv1_b   = (const float*)d_in[5];
  const float* in_proj_w = (const float*)d_in[6];
  const float* out_proj_w= (const float*)d_in[7];
  const float* conv2_w   = (const float*)d_in[8];
  const float* conv2_b   = (const float*)d_in[9];
  const float* q_w       = (const float*)d_in[10];
  const float* q_b       = (const float*)d_in[11];
  const float* k_w       = (const float*)d_in[12];
  const float* k_b       = (const float*)d_in[13];
  const float* logit_scale = (const float*)d_in[14];
  float* out = (float*)d_out;

  char* ws = (char*)d_ws;
  size_t off = 0;
  auto alloc = [&](size_t bytes) -> char* {
    char* p = ws + off;
    off += (bytes + 255) & ~(size_t)255;
    return p;
  };
  const size_t MROWS = 32 * 196; // 6272
  u16* bef16    = (u16*)alloc(MROWS * 512 * 2);
  u16* aft16    = (u16*)alloc(MROWS * 512 * 2);
  u16* w1a16    = (u16*)alloc(512 * 512 * 2);
  u16* inproj16 = (u16*)alloc(1536 * 512 * 2);
  u16* kw16     = (u16*)alloc(512 * 512 * 2);
  u16* qw16     = (u16*)alloc(512 * 512 * 2);
  u16* wcT16    = (u16*)alloc(512 * 512 * 2);
  u16* woT16    = (u16*)alloc(512 * 512 * 2);
  u16* wt16     = (u16*)alloc(512 * 512 * 2);
  u16* wcomb16  = (u16*)alloc(512 * 512 * 2);
  float* biasb  = (float*)alloc(32 * 512 * 4);
  float* biasq  = (float*)alloc(512 * 4);
  u16* v116     = (u16*)alloc(MROWS * 512 * 2);
  u16* qkv16    = (u16*)alloc(MROWS * 1536 * 2);
  u16* oattn16  = (u16*)alloc(MROWS * 512 * 2);
  u16* QL16     = (u16*)alloc(MROWS * 512 * 2);
  u16* KL16     = (u16*)alloc(MROWS * 512 * 2);
  u32* maxbuf   = (u32*)alloc(2 * 32 * 32 * 196 * 4); // rowmax | colmax
  float* Sws    = (float*)alloc(1024 * 4);
  u32* rowmax   = maxbuf;
  u32* colmax   = maxbuf + 32 * 32 * 196;

  // fused prep: all casts, transposes, sentbias, biasq, maxbuf init (one launch)
  k_prep<<<4842, 256, 0, stream>>>(bef, aft, sent, masks, conv1_w, conv1_b,
                                   in_proj_w, out_proj_w, conv2_w, conv2_b,
                                   q_w, q_b, k_w,
                                   bef16, aft16, inproj16, kw16, qw16,
                                   w1a16, wcT16, woT16, biasb, biasq,
                                   (uint4*)maxbuf);
  // [v1 = bef @ W1a^T + biasb[b]]  ||  [wt = Wq @ WcT]
  k_gemm3d<<<212, 256, 0, stream>>>(bef16, w1a16, v116, biasb, 49, 512, 2, 196,
                                    qw16, wcT16, wt16, nullptr, 4, 512, 0);
  // [qkv = v1 @ in_proj^T]  ||  [wcomb = wt @ WoT]
  k_gemm3d<<<604, 256, 0, stream>>>(v116, inproj16, qkv16, nullptr, 49, 1536, 0, 588,
                                    wt16, woT16, wcomb16, nullptr, 4, 512, 0);
  // attention (MFMA), 2 blocks per (b,h)
  k_attn2<<<512, 256, 0, stream>>>(qkv16, oattn16);
  // [QL = o_attn @ Wcomb^T + biasq]  ||  [KL = aft @ k_w^T + k_b]
  k_gemm3d<<<392, 256, 0, stream>>>(oattn16, wcomb16, QL16, biasq, 49, 512, 1, 196,
                                    aft16, kw16, KL16, k_b, 49, 512, 1);
  // logits reductions
  k_logits2<<<dim3(49, 32), 256, 0, stream>>>(QL16, KL16, rowmax, colmax);
  // S reduction + final loss
  k_sred<<<256, 256, 0, stream>>>(maxbuf, Sws);
  k_final<<<1, 1024, 0, stream>>>(Sws, logit_scale, out);
}